// Round 2
// baseline (301.396 us; speedup 1.0000x reference)
//
#include <hip/hip_runtime.h>

// Problem constants (fixed by the reference).
constexpr int N = 100000;   // nodes
constexpr int E = 1600000;  // edges
constexpr int D = 128;      // feature dim (both layers)
constexpr int M = 5000;     // mask size

constexpr int MF_BLKS = (N + 255) / 256;           // 391 mfma-gemm blocks (256 rows each)

// Counting-sort CSR build parameters.
// Bucket = dst>>7 (128 nodes). 782 buckets -> 782 local-sort blocks, enough TLP
// that the local phase is no longer a 196-block occupancy tail (R1: 7.7% occ, 55us).
constexpr int NBITS = 7;
constexpr int BUCKET = 1 << NBITS;                 // 128 nodes per bucket
constexpr int NB  = (N + BUCKET - 1) / BUCKET;     // 782 buckets
constexpr int EB  = 2048;                          // edges per hist/partition block
constexpr int NPB = (E + EB - 1) / EB;             // 782 partition blocks
constexpr int HL  = NB * NPB;                      // 611524 flat histogram entries
constexpr int SCCH = 4096;                         // scan chunk per block (16/thread)
constexpr int SC_BLKS = (HL + SCCH - 1) / SCCH;    // 150 scan blocks (<=256 for inline scan)
constexpr int PREP_BLKS = 64;                      // weight-prep blocks (16384 threads)
constexpr int MB_BLKS = (M + 255) / 256;           // 20 maskbit blocks

typedef __attribute__((ext_vector_type(8))) short bf16x8;
typedef __attribute__((ext_vector_type(4))) float f32x4;

// ---------------- bf16 helpers (RNE pack, cheap unpack) ----------------

__device__ __forceinline__ unsigned int pack_bf16x2(float a, float b) {
    unsigned int ua = __float_as_uint(a);
    unsigned int ub = __float_as_uint(b);
    ua = (ua + 0x7FFFu + ((ua >> 16) & 1u)) >> 16;
    ub = (ub + 0x7FFFu + ((ub >> 16) & 1u)) & 0xFFFF0000u;
    return ua | ub;
}
__device__ __forceinline__ unsigned short bf16_rne(float a) {
    unsigned int ua = __float_as_uint(a);
    return (unsigned short)((ua + 0x7FFFu + ((ua >> 16) & 1u)) >> 16);
}
__device__ __forceinline__ float bf16_lo(unsigned int u) { return __uint_as_float(u << 16); }
__device__ __forceinline__ float bf16_hi(unsigned int u) { return __uint_as_float(u & 0xFFFF0000u); }

// ---------------- misc1: hist (LDS atomics) + weight prep + maskbit ----------------

__global__ __launch_bounds__(256) void k_misc1(const int* __restrict__ dst,
                                               int* __restrict__ hist,
                                               const float* __restrict__ W1,
                                               unsigned int* __restrict__ Wt1,
                                               const float* __restrict__ W2,
                                               unsigned int* __restrict__ Wt2,
                                               const int* __restrict__ mask,
                                               unsigned int* __restrict__ maskbit,
                                               unsigned int* __restrict__ needed) {
    __shared__ int h[NB];
    const int t = threadIdx.x;
    if (blockIdx.x < NPB) {
        for (int i = t; i < NB; i += 256) h[i] = 0;
        __syncthreads();
        const int base = blockIdx.x * EB;
#pragma unroll
        for (int i = 0; i < 8; ++i) {
            int e = base + t + i * 256;
            if (e < E) {
                int b = __builtin_nontemporal_load(dst + e) >> NBITS;
                atomicAdd(&h[b], 1);
            }
        }
        __syncthreads();
        for (int i = t; i < NB; i += 256) hist[i * NPB + blockIdx.x] = h[i];
    } else if (blockIdx.x < NPB + PREP_BLKS) {
        int gi = (blockIdx.x - NPB) * 256 + t;   // 16384 total
        const float* W = (gi < 8192) ? W1 : W2;
        unsigned int* Wt = (gi < 8192) ? Wt1 : Wt2;
        int idx = gi & 8191;
        int n = idx >> 6, kk = idx & 63;
        float a = W[(2 * kk) * D + n];
        float b = W[(2 * kk + 1) * D + n];
        Wt[idx] = pack_bf16x2(a, b);
    } else {
        int i = (blockIdx.x - NPB - PREP_BLKS) * 256 + t;
        if (i < M) {
            int n = mask[i];
            atomicOr(&maskbit[n >> 5], 1u << (n & 31));
            atomicOr(&needed[n >> 5], 1u << (n & 31));  // masked nodes need their own row
        }
    }
}

// ---------------- misc2: scan partials (4096/block) + needed-set edge scan ----------------

__global__ __launch_bounds__(256) void k_misc2(const int* __restrict__ hist,
                                               int* __restrict__ bs,
                                               const unsigned int* __restrict__ maskbit,
                                               const int* __restrict__ src,
                                               const int* __restrict__ dst,
                                               unsigned int* __restrict__ needed) {
    __shared__ int ws_[4];
    const int t = threadIdx.x;
    if (blockIdx.x < SC_BLKS) {
        const int idx = blockIdx.x * SCCH + t * 16;
        int s = 0;
        if (idx + 15 < HL) {
#pragma unroll
            for (int g = 0; g < 4; ++g) {
                int4 c = *(const int4*)(hist + idx + g * 4);
                s += c.x + c.y + c.z + c.w;
            }
        } else {
            for (int g = 0; g < 16; ++g) if (idx + g < HL) s += hist[idx + g];
        }
        for (int off = 32; off > 0; off >>= 1) s += __shfl_down(s, off);
        if ((t & 63) == 0) ws_[t >> 6] = s;
        __syncthreads();
        if (t == 0) bs[blockIdx.x] = ws_[0] + ws_[1] + ws_[2] + ws_[3];
    } else {
        const int base = (blockIdx.x - SC_BLKS) * EB;
#pragma unroll
        for (int i = 0; i < 8; ++i) {
            int e = base + t + i * 256;
            if (e < E) {
                int d = __builtin_nontemporal_load(dst + e);
                if ((maskbit[d >> 5] >> (d & 31)) & 1u) {
                    int s = src[e];
                    atomicOr(&needed[s >> 5], 1u << (s & 31));
                }
            }
        }
    }
}

// ---- scan final: each block inline-scans the 150 block sums, then its 4096-chunk ----

__global__ __launch_bounds__(256) void k_scanf(const int* __restrict__ hist,
                                               const int* __restrict__ bs,
                                               int* __restrict__ histS) {
    __shared__ int sh[256];
    __shared__ int waveS[4];
    const int t = threadIdx.x;
    const int lane = t & 63;
    const int wave = t >> 6;

    sh[t] = (t < SC_BLKS) ? bs[t] : 0;
    __syncthreads();
    for (int off = 1; off < 256; off <<= 1) {
        int u = (t >= off) ? sh[t - off] : 0;
        __syncthreads();
        sh[t] += u;
        __syncthreads();
    }
    const int bOff = sh[blockIdx.x] - bs[blockIdx.x];

    const int idx = blockIdx.x * SCCH + t * 16;
    int c[16];
    if (idx + 15 < HL) {
#pragma unroll
        for (int g = 0; g < 4; ++g) {
            int4 q = *(const int4*)(hist + idx + g * 4);
            c[g * 4 + 0] = q.x; c[g * 4 + 1] = q.y; c[g * 4 + 2] = q.z; c[g * 4 + 3] = q.w;
        }
    } else {
#pragma unroll
        for (int g = 0; g < 16; ++g) c[g] = (idx + g < HL) ? hist[idx + g] : 0;
    }
    int s = 0;
#pragma unroll
    for (int g = 0; g < 16; ++g) s += c[g];

    int v = s;
    for (int off = 1; off < 64; off <<= 1) {
        int u = __shfl_up(v, off);
        if (lane >= off) v += u;
    }
    if (lane == 63) waveS[wave] = v;
    __syncthreads();
    int waveBase = 0;
    for (int w = 0; w < 4; ++w) if (w < wave) waveBase += waveS[w];
    int excl = bOff + waveBase + (v - s);

    int rs[16];
    int run = excl;
#pragma unroll
    for (int g = 0; g < 16; ++g) { rs[g] = run; run += c[g]; }
    if (idx + 15 < HL) {
#pragma unroll
        for (int g = 0; g < 4; ++g)
            *(int4*)(histS + idx + g * 4) = make_int4(rs[g * 4], rs[g * 4 + 1], rs[g * 4 + 2], rs[g * 4 + 3]);
    } else {
#pragma unroll
        for (int g = 0; g < 16; ++g) if (idx + g < HL) histS[idx + g] = rs[g];
    }
}

// ---------------- shared-memory union: GEMM W-tile OR local-sort arrays ----------------
// Fused kernels pay max(34816, ~1.6KB) = 34816 B, not the sum.

union SMem {
    unsigned int Ws[128 * 68];
    struct { int cnt[BUCKET]; float wsum[BUCKET]; int off[BUCKET]; int waveS[2]; } l;
};

// ---------------- MFMA GEMM body: 256 rows/block, 4 waves; wave = 64 rows x 128 cols ----------------
// A-frag: A[m=lane&15][k=quad*8+j]; B-frag: B[k=quad*8+j][n=lane&15];
// D: col=lane&15, row=quad*4+reg  (HW-verified layouts, 16x16x32 bf16).
// W^T staged in LDS with 68-uint row stride (bank-conflict padding).

template <bool BF16IN>
__device__ __forceinline__ void gemm_mfma_body(unsigned int* __restrict__ Ws,
                                               const void* __restrict__ Xin,
                                               const unsigned int* __restrict__ Wt,
                                               unsigned short* __restrict__ out, int blk) {
    const int t = threadIdx.x;
#pragma unroll
    for (int i = 0; i < 8; ++i) {
        int f4 = t + i * 256;        // uint4 index, 2048 total
        int n = f4 >> 4;
        int k4 = f4 & 15;
        uint4 w = ((const uint4*)Wt)[f4];
        *(uint4*)(&Ws[n * 68 + k4 * 4]) = w;
    }
    __syncthreads();

    const int wv = t >> 6, lane = t & 63;
    const int q = lane >> 4, l15 = lane & 15;
    const int rowBase = blk * 256 + wv * 64;

    f32x4 acc[4][8] = {};
#pragma unroll
    for (int kc = 0; kc < 4; ++kc) {
        bf16x8 af[4];
#pragma unroll
        for (int rt = 0; rt < 4; ++rt) {
            int row = rowBase + rt * 16 + l15;
            if (row > N - 1) row = N - 1;   // tail: duplicate last row, stores guarded
            union { uint4 u; bf16x8 v; } cv;
            if (BF16IN) {
                cv.u = *(const uint4*)((const unsigned int*)Xin + (size_t)row * 64 + kc * 16 + q * 4);
            } else {
                const float* xr = (const float*)Xin + (size_t)row * D + kc * 32 + q * 8;
                float4 x0 = *(const float4*)xr;
                float4 x1 = *(const float4*)(xr + 4);
                cv.u.x = pack_bf16x2(x0.x, x0.y);
                cv.u.y = pack_bf16x2(x0.z, x0.w);
                cv.u.z = pack_bf16x2(x1.x, x1.y);
                cv.u.w = pack_bf16x2(x1.z, x1.w);
            }
            af[rt] = cv.v;
        }
#pragma unroll
        for (int ct = 0; ct < 8; ++ct) {
            union { uint4 u; bf16x8 v; } bv;
            bv.u = *(const uint4*)(&Ws[(ct * 16 + l15) * 68 + kc * 16 + q * 4]);
#pragma unroll
            for (int rt = 0; rt < 4; ++rt)
                acc[rt][ct] = __builtin_amdgcn_mfma_f32_16x16x32_bf16(af[rt], bv.v, acc[rt][ct], 0, 0, 0);
        }
    }

#pragma unroll
    for (int rt = 0; rt < 4; ++rt) {
#pragma unroll
        for (int ct = 0; ct < 8; ++ct) {
            int col = ct * 16 + l15;
#pragma unroll
            for (int r = 0; r < 4; ++r) {
                int row = rowBase + rt * 16 + q * 4 + r;
                if (row < N) out[(size_t)row * D + col] = bf16_rne(acc[rt][ct][r]);
            }
        }
    }
}

// ---------------- partition: LEAN kernel (tiny LDS/VGPR -> full occupancy) ----------------
// record: bits[6:0]=d&127, bits[26:7]=src, bits[63:32]=ew bits

__global__ __launch_bounds__(256) void k_part(const int* __restrict__ src,
                                              const int* __restrict__ dst,
                                              const float* __restrict__ ew,
                                              const int* __restrict__ histS,
                                              unsigned long long* __restrict__ tmp) {
    __shared__ int base_[NB];
    const int t = threadIdx.x;
    for (int i = t; i < NB; i += 256) base_[i] = histS[i * NPB + blockIdx.x];
    __syncthreads();
    const int eb = blockIdx.x * EB;
#pragma unroll
    for (int i = 0; i < 8; ++i) {
        int e = eb + t + i * 256;
        if (e < E) {
            int d = __builtin_nontemporal_load(dst + e);
            int s = __builtin_nontemporal_load(src + e);
            float w = __builtin_nontemporal_load(ew + e);
            int b = d >> NBITS;
            int pos = atomicAdd(&base_[b], 1);
            unsigned long long rec =
                ((unsigned long long)(unsigned int)__float_as_int(w) << 32) |
                ((unsigned int)s << NBITS) | (unsigned int)(d & (BUCKET - 1));
            __builtin_nontemporal_store(rec, tmp + pos);
        }
    }
}

// ---- per-bucket local sort body; writes rowStart, dis, node-sorted pairs (src, raw ew) ----
// 128 nodes/bucket: threads 0..127 own one node each for the prefix/rowStart phase.

__device__ __forceinline__ void local_body(SMem& sm,
                                           const unsigned long long* __restrict__ tmp,
                                           const int* __restrict__ histS,
                                           float* __restrict__ dis,
                                           int* __restrict__ rowStart,
                                           int2* __restrict__ pairs) {
    const int b = blockIdx.x;
    const int t = threadIdx.x;
    const int segBeg = histS[b * NPB];
    const int segEnd = (b + 1 < NB) ? histS[(b + 1) * NPB] : E;

    int*   cnt   = sm.l.cnt;
    float* wsum  = sm.l.wsum;
    int*   off   = sm.l.off;
    int*   waveS = sm.l.waveS;
    if (t < BUCKET) { cnt[t] = 0; wsum[t] = 0.f; }
    __syncthreads();

    for (int e = segBeg + t; e < segEnd; e += 256) {
        unsigned long long rec = tmp[e];
        int dl = (int)(rec & (BUCKET - 1));
        float w = __uint_as_float((unsigned int)(rec >> 32));
        atomicAdd(&cnt[dl], 1);
        atomicAdd(&wsum[dl], w);
    }
    __syncthreads();

    const int lane = t & 63, wv = t >> 6;
    const int pv = (t < BUCKET) ? cnt[t] : 0;
    int v = pv;
    for (int o = 1; o < 64; o <<= 1) {
        int u = __shfl_up(v, o);
        if (lane >= o) v += u;
    }
    if (lane == 63 && wv < 2) waveS[wv] = v;
    __syncthreads();
    if (t < BUCKET) {
        const int wb = (wv == 1) ? waveS[0] : 0;
        const int ex = wb + v - pv;
        off[t] = ex;
        const int node = b * BUCKET + t;
        if (node < N) { rowStart[node] = segBeg + ex; dis[node] = rsqrtf(1.0f + wsum[t]); }
        cnt[t] = 0;
    }
    if (b == NB - 1 && t == 0) rowStart[N] = E;
    __syncthreads();

    for (int e = segBeg + t; e < segEnd; e += 256) {
        unsigned long long rec = tmp[e];
        int dl = (int)(rec & (BUCKET - 1));
        int s  = (int)((rec >> NBITS) & 0xFFFFF);
        unsigned int wbits = (unsigned int)(rec >> 32);
        int r = atomicAdd(&cnt[dl], 1);
        pairs[segBeg + off[dl] + r] = make_int2(s, (int)wbits);
    }
}

// ---------------- fused: local sort (blocks 0..NB) + GEMM1 A=x@W1 (blocks NB..NB+MF_BLKS) ----
// 782 + 391 = 1173 blocks ~ 4.6/CU of work vs the 3-block/CU VGPR cap: CUs stay fed,
// no 196-block occupancy tail (R1's 55us @ 7.7% occ).

__global__ __launch_bounds__(256) void k_local_g1(const unsigned long long* __restrict__ tmp,
                                                  const int* __restrict__ histS,
                                                  float* __restrict__ dis,
                                                  int* __restrict__ rowStart,
                                                  int2* __restrict__ pairs,
                                                  const float* __restrict__ x,
                                                  const unsigned int* __restrict__ Wt1,
                                                  unsigned short* __restrict__ A) {
    __shared__ SMem sm;
    if (blockIdx.x < NB) {
        local_body(sm, tmp, histS, dis, rowStart, pairs);
    } else {
        gemm_mfma_body<false>(sm.Ws, x, Wt1, A, blockIdx.x - NB);
    }
}

__global__ __launch_bounds__(256) void k_gemm2(const unsigned short* __restrict__ B,
                                               const unsigned int* __restrict__ Wt2,
                                               unsigned short* __restrict__ A2) {
    __shared__ SMem sm;
    gemm_mfma_body<true>(sm.Ws, B, Wt2, A2, blockIdx.x);
}

// ---------------- aggregate layer 1 (needed nodes only): B = relu(dis*sum + A/deg + b1) ----------------
// One wave per node; lane owns a col-pair. v = ew*dis[src] computed on the fly
// (pairs/dis loads are wave-uniform -> broadcast). 8 gathers in flight.

__global__ __launch_bounds__(256) void k_aggregate(const unsigned int* __restrict__ Hb,
                                                   const int2* __restrict__ pairs,
                                                   const int* __restrict__ rowStart,
                                                   const float* __restrict__ dis,
                                                   const unsigned int* __restrict__ needed,
                                                   const float* __restrict__ b,
                                                   unsigned int* __restrict__ outB) {
    int node = blockIdx.x * 4 + (threadIdx.x >> 6);
    if (node >= N) return;
    if (!((needed[node >> 5] >> (node & 31)) & 1u)) return;  // row never consumed downstream
    int lane = threadIdx.x & 63;
    int beg = rowStart[node], end = rowStart[node + 1];

    float ax = 0.f, ay = 0.f;
    int j = beg;
    for (; j + 7 < end; j += 8) {
        int2 p[8];
        float vv[8];
        unsigned int h[8];
#pragma unroll
        for (int i = 0; i < 8; ++i) p[i] = pairs[j + i];
#pragma unroll
        for (int i = 0; i < 8; ++i) { h[i] = Hb[(size_t)p[i].x * 64 + lane]; vv[i] = dis[p[i].x]; }
#pragma unroll
        for (int i = 0; i < 8; ++i) {
            float v = __int_as_float(p[i].y) * vv[i];
            ax += bf16_lo(h[i]) * v;
            ay += bf16_hi(h[i]) * v;
        }
    }
    for (; j + 3 < end; j += 4) {
        int2 p[4];
        float vv[4];
        unsigned int h[4];
#pragma unroll
        for (int i = 0; i < 4; ++i) p[i] = pairs[j + i];
#pragma unroll
        for (int i = 0; i < 4; ++i) { h[i] = Hb[(size_t)p[i].x * 64 + lane]; vv[i] = dis[p[i].x]; }
#pragma unroll
        for (int i = 0; i < 4; ++i) {
            float v = __int_as_float(p[i].y) * vv[i];
            ax += bf16_lo(h[i]) * v;
            ay += bf16_hi(h[i]) * v;
        }
    }
    for (; j < end; ++j) {
        int2 p0 = pairs[j];
        unsigned int h0 = Hb[(size_t)p0.x * 64 + lane];
        float v0 = __int_as_float(p0.y) * dis[p0.x];
        ax += bf16_lo(h0) * v0;
        ay += bf16_hi(h0) * v0;
    }

    float dd = dis[node];
    float sn = dd * dd;  // self-loop norm = 1/deg
    unsigned int hs = Hb[(size_t)node * 64 + lane];
    float2 bb = ((const float2*)b)[lane];
    float ox = fmaxf(ax * dd + bf16_lo(hs) * sn + bb.x, 0.f);
    float oy = fmaxf(ay * dd + bf16_hi(hs) * sn + bb.y, 0.f);
    __builtin_nontemporal_store(pack_bf16x2(ox, oy), outB + (size_t)node * 64 + lane);
}

// ---------------- layer-2 aggregate at mask nodes only -> d_out ----------------

__global__ __launch_bounds__(256) void k_aggregate_mask(const unsigned int* __restrict__ Hb,
                                                        const int2* __restrict__ pairs,
                                                        const int* __restrict__ rowStart,
                                                        const float* __restrict__ dis,
                                                        const float* __restrict__ b,
                                                        const int* __restrict__ mask,
                                                        const int* __restrict__ y,
                                                        float* __restrict__ out) {
    int i = blockIdx.x * 4 + (threadIdx.x >> 6);
    if (i >= M) return;
    int lane = threadIdx.x & 63;
    int node = mask[i];
    int beg = rowStart[node], end = rowStart[node + 1];

    float ax = 0.f, ay = 0.f;
    int j = beg;
    for (; j + 7 < end; j += 8) {
        int2 p[8];
        float vv[8];
        unsigned int h[8];
#pragma unroll
        for (int ii = 0; ii < 8; ++ii) p[ii] = pairs[j + ii];
#pragma unroll
        for (int ii = 0; ii < 8; ++ii) { h[ii] = Hb[(size_t)p[ii].x * 64 + lane]; vv[ii] = dis[p[ii].x]; }
#pragma unroll
        for (int ii = 0; ii < 8; ++ii) {
            float v = __int_as_float(p[ii].y) * vv[ii];
            ax += bf16_lo(h[ii]) * v;
            ay += bf16_hi(h[ii]) * v;
        }
    }
    for (; j < end; ++j) {
        int2 p0 = pairs[j];
        unsigned int h0 = Hb[(size_t)p0.x * 64 + lane];
        float v0 = __int_as_float(p0.y) * dis[p0.x];
        ax += bf16_lo(h0) * v0;
        ay += bf16_hi(h0) * v0;
    }

    float dd = dis[node];
    float sn = dd * dd;
    unsigned int hs = Hb[(size_t)node * 64 + lane];
    float2 bb = ((const float2*)b)[lane];
    float ox = ax * dd + bf16_lo(hs) * sn + bb.x;
    float oy = ay * dd + bf16_hi(hs) * sn + bb.y;
    ((float2*)(out + (size_t)i * D))[lane] = make_float2(ox, oy);
    if (lane == 0) out[(size_t)M * D + i] = (float)y[node];
}

extern "C" void kernel_launch(void* const* d_in, const int* in_sizes, int n_in,
                              void* d_out, int out_size, void* d_ws, size_t ws_size,
                              hipStream_t stream) {
    const float* x  = (const float*)d_in[0];
    const float* ew = (const float*)d_in[1];
    const float* W1 = (const float*)d_in[2];
    const float* b1 = (const float*)d_in[3];
    const float* W2 = (const float*)d_in[4];
    const float* b2 = (const float*)d_in[5];
    const int* eidx = (const int*)d_in[6];
    const int* mask = (const int*)d_in[7];
    const int* y    = (const int*)d_in[8];
    const int* src = eidx;       // edge_index[0]
    const int* dst = eidx + E;   // edge_index[1]

    // Workspace layout (bytes):
    //   dis       @ 0        : N f32       (0.4 MB)
    //   rowStart  @ 512 KB   : N+1 i32     (0.4 MB)
    //   scanBS    @ 1024 KB  : SC_BLKS i32
    //   maskbit   @ 1056 KB  : 16 KB bitmap  }  zeroed together (32 KB memset)
    //   needed    @ 1072 KB  : 16 KB bitmap  }
    //   Wt1       @ 1088 KB  : 8192 u32    (32 KB)
    //   Wt2       @ 1120 KB  : 8192 u32    (32 KB)
    //   hist      @ 1280 KB  : HL i32      (2.39 MB)
    //   histS     @ 3968 KB  : HL i32      (2.39 MB)
    //   pairs     @ 6656 KB  : E int2      (12.8 MB)
    //   tmp       @ 19.5 MB  : E u64       (12.8 MB)
    //   A  (bf16) @ 33 MB    : N*D bf16    (25.6 MB)  [A2 aliases A: A is dead after
    //   B  (bf16) @ 59 MB    : N*D bf16    (25.6 MB)   k_aggregate, before k_gemm2]
    //   total ~84.6 MB
    char* ws = (char*)d_ws;
    float* dis      = (float*)(ws);
    int*   rowStart = (int*)(ws + (size_t)512 * 1024);
    int*   scanBS   = (int*)(ws + (size_t)1024 * 1024);
    unsigned int* maskbit = (unsigned int*)(ws + (size_t)1056 * 1024);
    unsigned int* needed  = (unsigned int*)(ws + (size_t)1072 * 1024);
    unsigned int* Wt1 = (unsigned int*)(ws + (size_t)1088 * 1024);
    unsigned int* Wt2 = (unsigned int*)(ws + (size_t)1120 * 1024);
    int*   hist     = (int*)(ws + (size_t)1280 * 1024);
    int*   histS    = (int*)(ws + (size_t)3968 * 1024);
    int2*  pairs    = (int2*)(ws + (size_t)6656 * 1024);
    unsigned long long* tmp = (unsigned long long*)(ws + (size_t)19968 * 1024);
    unsigned short* A  = (unsigned short*)(ws + (size_t)33 * 1024 * 1024);
    unsigned short* B  = (unsigned short*)(ws + (size_t)59 * 1024 * 1024);
    unsigned short* A2 = A;   // alias: A consumed by k_aggregate before k_gemm2 writes A2

    // --- zero bitmaps, then fused hist + weight prep + maskbit ---
    (void)hipMemsetAsync(maskbit, 0, (size_t)32 * 1024, stream);
    hipLaunchKernelGGL(k_misc1, dim3(NPB + PREP_BLKS + MB_BLKS), dim3(256), 0, stream,
                       dst, hist, W1, Wt1, W2, Wt2, mask, maskbit, needed);

    // --- fused scan partials + needed-set edge scan ---
    hipLaunchKernelGGL(k_misc2, dim3(SC_BLKS + NPB), dim3(256), 0, stream,
                       hist, scanBS, maskbit, src, dst, needed);
    hipLaunchKernelGGL(k_scanf, dim3(SC_BLKS), dim3(256), 0, stream, hist, scanBS, histS);

    // --- lean partition (full occupancy), then fused local-sort + GEMM1 ---
    hipLaunchKernelGGL(k_part, dim3(NPB), dim3(256), 0, stream,
                       src, dst, ew, histS, tmp);
    hipLaunchKernelGGL(k_local_g1, dim3(NB + MF_BLKS), dim3(256), 0, stream,
                       tmp, histS, dis, rowStart, pairs, x, Wt1, A);

    // --- layer 1 aggregate at needed nodes only: B = relu(agg(A) + b1) ---
    hipLaunchKernelGGL(k_aggregate, dim3((N + 3) / 4), dim3(256), 0, stream,
                       (const unsigned int*)A, pairs, rowStart, dis, needed, b1,
                       (unsigned int*)B);

    // --- layer 2: A2 = B@W2 (MFMA) ; out = agg(A2) at mask nodes ---
    hipLaunchKernelGGL(k_gemm2, dim3(MF_BLKS), dim3(256), 0, stream, B, Wt2, A2);
    hipLaunchKernelGGL(k_aggregate_mask, dim3((M + 3) / 4), dim3(256), 0, stream,
                       (const unsigned int*)A2, pairs, rowStart, dis, b2, mask, y, (float*)d_out);
}

// Round 3
// 270.351 us; speedup vs baseline: 1.1148x; 1.1148x over previous
//
#include <hip/hip_runtime.h>

// Problem constants (fixed by the reference).
constexpr int N = 100000;   // nodes
constexpr int E = 1600000;  // edges
constexpr int D = 128;      // feature dim (both layers)
constexpr int M = 5000;     // mask size

constexpr int MF_BLKS = (N + 255) / 256;           // 391 mfma-gemm blocks (256 rows each)

// Counting-sort CSR build parameters.
// Bucket = dst>>7 (128 nodes) -> 782 buckets / 782 local-sort blocks (R2: local TLP fix).
// Partition uses atomic run-reservation (no per-(bucket,block) scan): each partition
// block reserves a contiguous run per bucket via atomicAdd on a global cursor, so runs
// average EBP/NB = 10.5 records (84B >= 1 line) and L2 merges the scatter (R2 showed
// 3.84x write amplification = 49MB for a 12.8MB payload with 2.6-record runs).
constexpr int NBITS = 7;
constexpr int BUCKET = 1 << NBITS;                 // 128 nodes per bucket
constexpr int NB  = (N + BUCKET - 1) / BUCKET;     // 782 buckets
constexpr int EB  = 2048;                          // edges per hist/needed-scan block
constexpr int NPB = (E + EB - 1) / EB;             // 782 hist / needed-scan blocks
constexpr int EBP = 8192;                          // edges per partition block
constexpr int NPP = (E + EBP - 1) / EBP;           // 196 partition blocks (1024 thr each)
constexpr int PREP_BLKS = 64;                      // weight-prep blocks (16384 threads)
constexpr int MB_BLKS = (M + 255) / 256;           // 20 maskbit blocks

typedef __attribute__((ext_vector_type(8))) short bf16x8;
typedef __attribute__((ext_vector_type(4))) float f32x4;

// ---------------- bf16 helpers (RNE pack, cheap unpack) ----------------

__device__ __forceinline__ unsigned int pack_bf16x2(float a, float b) {
    unsigned int ua = __float_as_uint(a);
    unsigned int ub = __float_as_uint(b);
    ua = (ua + 0x7FFFu + ((ua >> 16) & 1u)) >> 16;
    ub = (ub + 0x7FFFu + ((ub >> 16) & 1u)) & 0xFFFF0000u;
    return ua | ub;
}
__device__ __forceinline__ unsigned short bf16_rne(float a) {
    unsigned int ua = __float_as_uint(a);
    return (unsigned short)((ua + 0x7FFFu + ((ua >> 16) & 1u)) >> 16);
}
__device__ __forceinline__ float bf16_lo(unsigned int u) { return __uint_as_float(u << 16); }
__device__ __forceinline__ float bf16_hi(unsigned int u) { return __uint_as_float(u & 0xFFFF0000u); }

// ---------------- misc1: bucket hist (LDS + global atomics) + weight prep + maskbit ----------------

__global__ __launch_bounds__(256) void k_misc1(const int* __restrict__ dst,
                                               int* __restrict__ bucketCnt,
                                               const float* __restrict__ W1,
                                               unsigned int* __restrict__ Wt1,
                                               const float* __restrict__ W2,
                                               unsigned int* __restrict__ Wt2,
                                               const int* __restrict__ mask,
                                               unsigned int* __restrict__ maskbit,
                                               unsigned int* __restrict__ needed) {
    __shared__ int h[NB];
    const int t = threadIdx.x;
    if (blockIdx.x < NPB) {
        for (int i = t; i < NB; i += 256) h[i] = 0;
        __syncthreads();
        const int base = blockIdx.x * EB;
#pragma unroll
        for (int i = 0; i < 8; ++i) {
            int e = base + t + i * 256;
            if (e < E) {
                int b = __builtin_nontemporal_load(dst + e) >> NBITS;
                atomicAdd(&h[b], 1);
            }
        }
        __syncthreads();
        for (int i = t; i < NB; i += 256) {
            int c = h[i];
            if (c) atomicAdd(&bucketCnt[i], c);
        }
    } else if (blockIdx.x < NPB + PREP_BLKS) {
        int gi = (blockIdx.x - NPB) * 256 + t;   // 16384 total
        const float* W = (gi < 8192) ? W1 : W2;
        unsigned int* Wt = (gi < 8192) ? Wt1 : Wt2;
        int idx = gi & 8191;
        int n = idx >> 6, kk = idx & 63;
        float a = W[(2 * kk) * D + n];
        float b = W[(2 * kk + 1) * D + n];
        Wt[idx] = pack_bf16x2(a, b);
    } else {
        int i = (blockIdx.x - NPB - PREP_BLKS) * 256 + t;
        if (i < M) {
            int n = mask[i];
            atomicOr(&maskbit[n >> 5], 1u << (n & 31));
            atomicOr(&needed[n >> 5], 1u << (n & 31));  // masked nodes need their own row
        }
    }
}

// ---------------- misc2: bucket scan (1 block) + needed-set edge scan (NPB blocks) ----------------

__global__ __launch_bounds__(256) void k_misc2(const int* __restrict__ bucketCnt,
                                               int* __restrict__ bucketBase,
                                               int* __restrict__ gCursor,
                                               const unsigned int* __restrict__ maskbit,
                                               const int* __restrict__ src,
                                               const int* __restrict__ dst,
                                               unsigned int* __restrict__ needed) {
    const int t = threadIdx.x;
    if (blockIdx.x == 0) {
        // exclusive scan of bucketCnt[0..NB) -> bucketBase[0..NB]; copy to gCursor.
        __shared__ int waveS[4];
        const int lane = t & 63, wave = t >> 6;
        const int idx = t * 4;
        int c[4];
        int s = 0;
#pragma unroll
        for (int g = 0; g < 4; ++g) {
            c[g] = (idx + g < NB) ? bucketCnt[idx + g] : 0;
            s += c[g];
        }
        int v = s;
        for (int off = 1; off < 64; off <<= 1) {
            int u = __shfl_up(v, off);
            if (lane >= off) v += u;
        }
        if (lane == 63) waveS[wave] = v;
        __syncthreads();
        int wb = 0;
        for (int w = 0; w < 4; ++w) if (w < wave) wb += waveS[w];
        int run = wb + v - s;   // exclusive prefix
#pragma unroll
        for (int g = 0; g < 4; ++g) {
            int pos = idx + g;
            if (pos < NB) {
                bucketBase[pos] = run;
                gCursor[pos] = run;
            } else if (pos == NB) {
                bucketBase[NB] = run;   // == E
            }
            run += c[g];
        }
        if (t == 255) bucketBase[NB] = E;  // ensure sentinel even if NB < 4*256 boundary math shifts
    } else {
        const int base = (blockIdx.x - 1) * EB;
#pragma unroll
        for (int i = 0; i < 8; ++i) {
            int e = base + t + i * 256;
            if (e < E) {
                int d = __builtin_nontemporal_load(dst + e);
                if ((maskbit[d >> 5] >> (d & 31)) & 1u) {
                    int s = src[e];
                    atomicOr(&needed[s >> 5], 1u << (s & 31));
                }
            }
        }
    }
}

// ---------------- partition: register-stash + atomic run reservation ----------------
// 1024-thread blocks, 8 edges/thread in VGPRs (single global read). Phase 1: LDS count.
// Phase 2: one global atomicAdd per nonempty bucket reserves a contiguous run.
// Phase 3: scatter into the run with CACHED stores (runs ~84B -> L2 merges to full lines).
// record: bits[6:0]=d&127, bits[23:7]=src, bits[63:32]=ew bits

__global__ __launch_bounds__(1024) void k_part(const int* __restrict__ src,
                                               const int* __restrict__ dst,
                                               const float* __restrict__ ew,
                                               int* __restrict__ gCursor,
                                               unsigned long long* __restrict__ tmp) {
    __shared__ int cnt[NB];
    __shared__ int off[NB];
    __shared__ int rk[NB];
    const int t = threadIdx.x;
    for (int i = t; i < NB; i += 1024) { cnt[i] = 0; rk[i] = 0; }
    __syncthreads();

    const int eb = blockIdx.x * EBP;
    int d_[8], s_[8];
    float w_[8];
#pragma unroll
    for (int i = 0; i < 8; ++i) {
        int e = eb + t + i * 1024;
        if (e < E) {
            d_[i] = __builtin_nontemporal_load(dst + e);
            s_[i] = __builtin_nontemporal_load(src + e);
            w_[i] = __builtin_nontemporal_load(ew + e);
            atomicAdd(&cnt[d_[i] >> NBITS], 1);
        } else {
            d_[i] = -1;
        }
    }
    __syncthreads();

    for (int i = t; i < NB; i += 1024) {
        int c = cnt[i];
        if (c > 0) off[i] = atomicAdd(&gCursor[i], c);
    }
    __syncthreads();

#pragma unroll
    for (int i = 0; i < 8; ++i) {
        if (d_[i] >= 0) {
            int b = d_[i] >> NBITS;
            int r = atomicAdd(&rk[b], 1);
            unsigned long long rec =
                ((unsigned long long)(unsigned int)__float_as_int(w_[i]) << 32) |
                ((unsigned int)s_[i] << NBITS) | (unsigned int)(d_[i] & (BUCKET - 1));
            tmp[(size_t)off[b] + r] = rec;   // cached store: let L2 merge run into full lines
        }
    }
}

// ---------------- shared-memory union: GEMM W-tile OR local-sort arrays ----------------

union SMem {
    unsigned int Ws[128 * 68];
    struct { int cnt[BUCKET]; float wsum[BUCKET]; int off[BUCKET]; int waveS[2]; } l;
};

// ---------------- MFMA GEMM body: 256 rows/block, 4 waves; wave = 64 rows x 128 cols ----------------
// A-frag: A[m=lane&15][k=quad*8+j]; B-frag: B[k=quad*8+j][n=lane&15];
// D: col=lane&15, row=quad*4+reg  (HW-verified layouts, 16x16x32 bf16).
// W^T staged in LDS with 68-uint row stride (bank-conflict padding).

template <bool BF16IN>
__device__ __forceinline__ void gemm_mfma_body(unsigned int* __restrict__ Ws,
                                               const void* __restrict__ Xin,
                                               const unsigned int* __restrict__ Wt,
                                               unsigned short* __restrict__ out, int blk) {
    const int t = threadIdx.x;
#pragma unroll
    for (int i = 0; i < 8; ++i) {
        int f4 = t + i * 256;        // uint4 index, 2048 total
        int n = f4 >> 4;
        int k4 = f4 & 15;
        uint4 w = ((const uint4*)Wt)[f4];
        *(uint4*)(&Ws[n * 68 + k4 * 4]) = w;
    }
    __syncthreads();

    const int wv = t >> 6, lane = t & 63;
    const int q = lane >> 4, l15 = lane & 15;
    const int rowBase = blk * 256 + wv * 64;

    f32x4 acc[4][8] = {};
#pragma unroll
    for (int kc = 0; kc < 4; ++kc) {
        bf16x8 af[4];
#pragma unroll
        for (int rt = 0; rt < 4; ++rt) {
            int row = rowBase + rt * 16 + l15;
            if (row > N - 1) row = N - 1;   // tail: duplicate last row, stores guarded
            union { uint4 u; bf16x8 v; } cv;
            if (BF16IN) {
                cv.u = *(const uint4*)((const unsigned int*)Xin + (size_t)row * 64 + kc * 16 + q * 4);
            } else {
                const float* xr = (const float*)Xin + (size_t)row * D + kc * 32 + q * 8;
                float4 x0 = *(const float4*)xr;
                float4 x1 = *(const float4*)(xr + 4);
                cv.u.x = pack_bf16x2(x0.x, x0.y);
                cv.u.y = pack_bf16x2(x0.z, x0.w);
                cv.u.z = pack_bf16x2(x1.x, x1.y);
                cv.u.w = pack_bf16x2(x1.z, x1.w);
            }
            af[rt] = cv.v;
        }
#pragma unroll
        for (int ct = 0; ct < 8; ++ct) {
            union { uint4 u; bf16x8 v; } bv;
            bv.u = *(const uint4*)(&Ws[(ct * 16 + l15) * 68 + kc * 16 + q * 4]);
#pragma unroll
            for (int rt = 0; rt < 4; ++rt)
                acc[rt][ct] = __builtin_amdgcn_mfma_f32_16x16x32_bf16(af[rt], bv.v, acc[rt][ct], 0, 0, 0);
        }
    }

#pragma unroll
    for (int rt = 0; rt < 4; ++rt) {
#pragma unroll
        for (int ct = 0; ct < 8; ++ct) {
            int col = ct * 16 + l15;
#pragma unroll
            for (int r = 0; r < 4; ++r) {
                int row = rowBase + rt * 16 + q * 4 + r;
                if (row < N) out[(size_t)row * D + col] = bf16_rne(acc[rt][ct][r]);
            }
        }
    }
}

// ---- per-bucket local sort body; writes rowStart, dis, node-sorted pairs (src, raw ew) ----
// 128 nodes/bucket: threads 0..127 own one node each for the prefix/rowStart phase.

__device__ __forceinline__ void local_body(SMem& sm,
                                           const unsigned long long* __restrict__ tmp,
                                           const int* __restrict__ bucketBase,
                                           float* __restrict__ dis,
                                           int* __restrict__ rowStart,
                                           int2* __restrict__ pairs) {
    const int b = blockIdx.x;
    const int t = threadIdx.x;
    const int segBeg = bucketBase[b];
    const int segEnd = bucketBase[b + 1];

    int*   cnt   = sm.l.cnt;
    float* wsum  = sm.l.wsum;
    int*   off   = sm.l.off;
    int*   waveS = sm.l.waveS;
    if (t < BUCKET) { cnt[t] = 0; wsum[t] = 0.f; }
    __syncthreads();

    for (int e = segBeg + t; e < segEnd; e += 256) {
        unsigned long long rec = tmp[e];
        int dl = (int)(rec & (BUCKET - 1));
        float w = __uint_as_float((unsigned int)(rec >> 32));
        atomicAdd(&cnt[dl], 1);
        atomicAdd(&wsum[dl], w);
    }
    __syncthreads();

    const int lane = t & 63, wv = t >> 6;
    const int pv = (t < BUCKET) ? cnt[t] : 0;
    int v = pv;
    for (int o = 1; o < 64; o <<= 1) {
        int u = __shfl_up(v, o);
        if (lane >= o) v += u;
    }
    if (lane == 63 && wv < 2) waveS[wv] = v;
    __syncthreads();
    if (t < BUCKET) {
        const int wb = (wv == 1) ? waveS[0] : 0;
        const int ex = wb + v - pv;
        off[t] = ex;
        const int node = b * BUCKET + t;
        if (node < N) { rowStart[node] = segBeg + ex; dis[node] = rsqrtf(1.0f + wsum[t]); }
        cnt[t] = 0;
    }
    if (b == NB - 1 && t == 0) rowStart[N] = E;
    __syncthreads();

    for (int e = segBeg + t; e < segEnd; e += 256) {
        unsigned long long rec = tmp[e];
        int dl = (int)(rec & (BUCKET - 1));
        int s  = (int)((rec >> NBITS) & 0xFFFFF);
        unsigned int wbits = (unsigned int)(rec >> 32);
        int r = atomicAdd(&cnt[dl], 1);
        pairs[segBeg + off[dl] + r] = make_int2(s, (int)wbits);
    }
}

// ---------------- fused: local sort (blocks 0..NB) + GEMM1 A=x@W1 (blocks NB..NB+MF_BLKS) ----

__global__ __launch_bounds__(256) void k_local_g1(const unsigned long long* __restrict__ tmp,
                                                  const int* __restrict__ bucketBase,
                                                  float* __restrict__ dis,
                                                  int* __restrict__ rowStart,
                                                  int2* __restrict__ pairs,
                                                  const float* __restrict__ x,
                                                  const unsigned int* __restrict__ Wt1,
                                                  unsigned short* __restrict__ A) {
    __shared__ SMem sm;
    if (blockIdx.x < NB) {
        local_body(sm, tmp, bucketBase, dis, rowStart, pairs);
    } else {
        gemm_mfma_body<false>(sm.Ws, x, Wt1, A, blockIdx.x - NB);
    }
}

__global__ __launch_bounds__(256) void k_gemm2(const unsigned short* __restrict__ B,
                                               const unsigned int* __restrict__ Wt2,
                                               unsigned short* __restrict__ A2) {
    __shared__ SMem sm;
    gemm_mfma_body<true>(sm.Ws, B, Wt2, A2, blockIdx.x);
}

// ---------------- aggregate layer 1 (needed nodes only): B = relu(dis*sum + A/deg + b1) ----------------

__global__ __launch_bounds__(256) void k_aggregate(const unsigned int* __restrict__ Hb,
                                                   const int2* __restrict__ pairs,
                                                   const int* __restrict__ rowStart,
                                                   const float* __restrict__ dis,
                                                   const unsigned int* __restrict__ needed,
                                                   const float* __restrict__ b,
                                                   unsigned int* __restrict__ outB) {
    int node = blockIdx.x * 4 + (threadIdx.x >> 6);
    if (node >= N) return;
    if (!((needed[node >> 5] >> (node & 31)) & 1u)) return;  // row never consumed downstream
    int lane = threadIdx.x & 63;
    int beg = rowStart[node], end = rowStart[node + 1];

    float ax = 0.f, ay = 0.f;
    int j = beg;
    for (; j + 7 < end; j += 8) {
        int2 p[8];
        float vv[8];
        unsigned int h[8];
#pragma unroll
        for (int i = 0; i < 8; ++i) p[i] = pairs[j + i];
#pragma unroll
        for (int i = 0; i < 8; ++i) { h[i] = Hb[(size_t)p[i].x * 64 + lane]; vv[i] = dis[p[i].x]; }
#pragma unroll
        for (int i = 0; i < 8; ++i) {
            float v = __int_as_float(p[i].y) * vv[i];
            ax += bf16_lo(h[i]) * v;
            ay += bf16_hi(h[i]) * v;
        }
    }
    for (; j + 3 < end; j += 4) {
        int2 p[4];
        float vv[4];
        unsigned int h[4];
#pragma unroll
        for (int i = 0; i < 4; ++i) p[i] = pairs[j + i];
#pragma unroll
        for (int i = 0; i < 4; ++i) { h[i] = Hb[(size_t)p[i].x * 64 + lane]; vv[i] = dis[p[i].x]; }
#pragma unroll
        for (int i = 0; i < 4; ++i) {
            float v = __int_as_float(p[i].y) * vv[i];
            ax += bf16_lo(h[i]) * v;
            ay += bf16_hi(h[i]) * v;
        }
    }
    for (; j < end; ++j) {
        int2 p0 = pairs[j];
        unsigned int h0 = Hb[(size_t)p0.x * 64 + lane];
        float v0 = __int_as_float(p0.y) * dis[p0.x];
        ax += bf16_lo(h0) * v0;
        ay += bf16_hi(h0) * v0;
    }

    float dd = dis[node];
    float sn = dd * dd;  // self-loop norm = 1/deg
    unsigned int hs = Hb[(size_t)node * 64 + lane];
    float2 bb = ((const float2*)b)[lane];
    float ox = fmaxf(ax * dd + bf16_lo(hs) * sn + bb.x, 0.f);
    float oy = fmaxf(ay * dd + bf16_hi(hs) * sn + bb.y, 0.f);
    __builtin_nontemporal_store(pack_bf16x2(ox, oy), outB + (size_t)node * 64 + lane);
}

// ---------------- layer-2 aggregate at mask nodes only -> d_out ----------------

__global__ __launch_bounds__(256) void k_aggregate_mask(const unsigned int* __restrict__ Hb,
                                                        const int2* __restrict__ pairs,
                                                        const int* __restrict__ rowStart,
                                                        const float* __restrict__ dis,
                                                        const float* __restrict__ b,
                                                        const int* __restrict__ mask,
                                                        const int* __restrict__ y,
                                                        float* __restrict__ out) {
    int i = blockIdx.x * 4 + (threadIdx.x >> 6);
    if (i >= M) return;
    int lane = threadIdx.x & 63;
    int node = mask[i];
    int beg = rowStart[node], end = rowStart[node + 1];

    float ax = 0.f, ay = 0.f;
    int j = beg;
    for (; j + 7 < end; j += 8) {
        int2 p[8];
        float vv[8];
        unsigned int h[8];
#pragma unroll
        for (int ii = 0; ii < 8; ++ii) p[ii] = pairs[j + ii];
#pragma unroll
        for (int ii = 0; ii < 8; ++ii) { h[ii] = Hb[(size_t)p[ii].x * 64 + lane]; vv[ii] = dis[p[ii].x]; }
#pragma unroll
        for (int ii = 0; ii < 8; ++ii) {
            float v = __int_as_float(p[ii].y) * vv[ii];
            ax += bf16_lo(h[ii]) * v;
            ay += bf16_hi(h[ii]) * v;
        }
    }
    for (; j < end; ++j) {
        int2 p0 = pairs[j];
        unsigned int h0 = Hb[(size_t)p0.x * 64 + lane];
        float v0 = __int_as_float(p0.y) * dis[p0.x];
        ax += bf16_lo(h0) * v0;
        ay += bf16_hi(h0) * v0;
    }

    float dd = dis[node];
    float sn = dd * dd;
    unsigned int hs = Hb[(size_t)node * 64 + lane];
    float2 bb = ((const float2*)b)[lane];
    float ox = ax * dd + bf16_lo(hs) * sn + bb.x;
    float oy = ay * dd + bf16_hi(hs) * sn + bb.y;
    ((float2*)(out + (size_t)i * D))[lane] = make_float2(ox, oy);
    if (lane == 0) out[(size_t)M * D + i] = (float)y[node];
}

extern "C" void kernel_launch(void* const* d_in, const int* in_sizes, int n_in,
                              void* d_out, int out_size, void* d_ws, size_t ws_size,
                              hipStream_t stream) {
    const float* x  = (const float*)d_in[0];
    const float* ew = (const float*)d_in[1];
    const float* W1 = (const float*)d_in[2];
    const float* b1 = (const float*)d_in[3];
    const float* W2 = (const float*)d_in[4];
    const float* b2 = (const float*)d_in[5];
    const int* eidx = (const int*)d_in[6];
    const int* mask = (const int*)d_in[7];
    const int* y    = (const int*)d_in[8];
    const int* src = eidx;       // edge_index[0]
    const int* dst = eidx + E;   // edge_index[1]

    // Workspace layout (bytes):
    //   dis        @ 0       : N f32       (0.4 MB)
    //   rowStart   @ 512 KB  : N+1 i32     (0.4 MB)
    //   maskbit    @ 960 KB  : 16 KB bitmap }
    //   needed     @ 976 KB  : 16 KB bitmap }  zeroed together (40 KB memset)
    //   bucketCnt  @ 992 KB  : NB i32 (3.1 KB) }
    //   bucketBase @ 996 KB  : NB+1 i32        (overwritten by misc2 scan)
    //   gCursor    @ 1000 KB : NB i32          (overwritten by misc2 scan)
    //   Wt1        @ 1008 KB : 8192 u32   (32 KB)
    //   Wt2        @ 1040 KB : 8192 u32   (32 KB)
    //   pairs      @ 2 MB    : E int2     (12.8 MB)
    //   tmp        @ 16 MB   : E u64      (12.8 MB)
    //   A  (bf16)  @ 29 MB   : N*D bf16   (25.6 MB)  [A2 aliases A: A dead after k_aggregate]
    //   B  (bf16)  @ 55 MB   : N*D bf16   (25.6 MB)   total ~81 MB
    char* ws = (char*)d_ws;
    float* dis      = (float*)(ws);
    int*   rowStart = (int*)(ws + (size_t)512 * 1024);
    unsigned int* maskbit = (unsigned int*)(ws + (size_t)960 * 1024);
    unsigned int* needed  = (unsigned int*)(ws + (size_t)976 * 1024);
    int*   bucketCnt  = (int*)(ws + (size_t)992 * 1024);
    int*   bucketBase = (int*)(ws + (size_t)996 * 1024);
    int*   gCursor    = (int*)(ws + (size_t)1000 * 1024);
    unsigned int* Wt1 = (unsigned int*)(ws + (size_t)1008 * 1024);
    unsigned int* Wt2 = (unsigned int*)(ws + (size_t)1040 * 1024);
    int2*  pairs    = (int2*)(ws + (size_t)2 * 1024 * 1024);
    unsigned long long* tmp = (unsigned long long*)(ws + (size_t)16 * 1024 * 1024);
    unsigned short* A  = (unsigned short*)(ws + (size_t)29 * 1024 * 1024);
    unsigned short* B  = (unsigned short*)(ws + (size_t)55 * 1024 * 1024);
    unsigned short* A2 = A;   // alias: A consumed by k_aggregate before k_gemm2 writes A2

    // --- zero bitmaps + bucket counters, then fused hist + weight prep + maskbit ---
    (void)hipMemsetAsync(ws + (size_t)960 * 1024, 0, (size_t)40 * 1024, stream);
    hipLaunchKernelGGL(k_misc1, dim3(NPB + PREP_BLKS + MB_BLKS), dim3(256), 0, stream,
                       dst, bucketCnt, W1, Wt1, W2, Wt2, mask, maskbit, needed);

    // --- bucket scan (1 block) + needed-set edge scan ---
    hipLaunchKernelGGL(k_misc2, dim3(1 + NPB), dim3(256), 0, stream,
                       bucketCnt, bucketBase, gCursor, maskbit, src, dst, needed);

    // --- partition via atomic run reservation ---
    hipLaunchKernelGGL(k_part, dim3(NPP), dim3(1024), 0, stream,
                       src, dst, ew, gCursor, tmp);
    hipLaunchKernelGGL(k_local_g1, dim3(NB + MF_BLKS), dim3(256), 0, stream,
                       tmp, bucketBase, dis, rowStart, pairs, x, Wt1, A);

    // --- layer 1 aggregate at needed nodes only: B = relu(agg(A) + b1) ---
    hipLaunchKernelGGL(k_aggregate, dim3((N + 3) / 4), dim3(256), 0, stream,
                       (const unsigned int*)A, pairs, rowStart, dis, needed, b1,
                       (unsigned int*)B);

    // --- layer 2: A2 = B@W2 (MFMA) ; out = agg(A2) at mask nodes ---
    hipLaunchKernelGGL(k_gemm2, dim3(MF_BLKS), dim3(256), 0, stream, B, Wt2, A2);
    hipLaunchKernelGGL(k_aggregate_mask, dim3((M + 3) / 4), dim3(256), 0, stream,
                       (const unsigned int*)A2, pairs, rowStart, dis, b2, mask, y, (float*)d_out);
}